// Round 1
// baseline (190.228 us; speedup 1.0000x reference)
//
#include <hip/hip_runtime.h>

// One workgroup (256 threads) per batch row b in [0,4096).
// Key restructuring vs reference: the 32x32 second-layer matmuls and the
// pooling commute (no relu between them), so we pool the 32-dim relu outputs
// first and apply w_p2/w_c2 once per row instead of once per token.
// Masked tokens (t >= lengths[b]) contribute exactly zero -> never loaded.

#define BDIM 256

__global__ __launch_bounds__(BDIM)
void mlpreg_kernel(const float* __restrict__ cont_p,
                   const float* __restrict__ cont_c,
                   const int* __restrict__ cat_p,
                   const int* __restrict__ cat_c,
                   const int* __restrict__ lengths,
                   const float* __restrict__ w_p1, const float* __restrict__ b_p1,
                   const float* __restrict__ w_p2, const float* __restrict__ b_p2,
                   const float* __restrict__ w_c1, const float* __restrict__ b_c1,
                   const float* __restrict__ w_c2, const float* __restrict__ b_c2,
                   const float* __restrict__ emb_g,  const float* __restrict__ emb_k,
                   const float* __restrict__ emb_pr, const float* __restrict__ emb_j,
                   const float* __restrict__ emb_r,  const float* __restrict__ emb_pl,
                   const float* __restrict__ emb_a,
                   const float* __restrict__ w_fc1, const float* __restrict__ b_fc1,
                   const float* __restrict__ w_fc2, const float* __restrict__ b_fc2,
                   float* __restrict__ out)
{
    constexpr int S = 256;
    // Embedding tables concatenated, 32-float-aligned rows:
    // eg @0 (2 rows), ek @2, epr @4, ej @6 (11), er @17 (34), epl @51 (19), ea @70 (31)
    __shared__ float tb[101 * 32];       // 12928 B
    __shared__ float sContP[S * 3];      // 3072 B
    __shared__ float sContC[S * 2];      // 2048 B
    __shared__ int   sCatP[S * 5];       // 5120 B
    __shared__ int   sCatC[S * 2];       // 2048 B
    __shared__ float sRed[BDIM];         // 1024 B
    __shared__ float sPooled[128];       //  512 B
    __shared__ float sPacc[64];          //  256 B  (pre-matmul pooled relu sums)
    __shared__ float sH[64];             //  256 B

    const int tid = threadIdx.x;
    const int b   = blockIdx.x;
    int L = lengths[b];
    if (L < 1) L = 1;
    if (L > S) L = S;

    // ---- stage embedding tables (per-WG; small, L2-resident across WGs) ----
    for (int i = tid; i < 2 * 32;  i += BDIM) tb[0 * 32 + i]  = emb_g[i];
    for (int i = tid; i < 2 * 32;  i += BDIM) tb[2 * 32 + i]  = emb_k[i];
    for (int i = tid; i < 2 * 32;  i += BDIM) tb[4 * 32 + i]  = emb_pr[i];
    for (int i = tid; i < 11 * 32; i += BDIM) tb[6 * 32 + i]  = emb_j[i];
    for (int i = tid; i < 34 * 32; i += BDIM) tb[17 * 32 + i] = emb_r[i];
    for (int i = tid; i < 19 * 32; i += BDIM) tb[51 * 32 + i] = emb_pl[i];
    for (int i = tid; i < 31 * 32; i += BDIM) tb[70 * 32 + i] = emb_a[i];

    // ---- stage token data: only the first L tokens (rest are masked out) ----
    {
        const float* gp = cont_p + (size_t)b * (S * 3);
        for (int i = tid; i < L * 3; i += BDIM) sContP[i] = gp[i];
        const float* gc = cont_c + (size_t)b * (S * 2);
        for (int i = tid; i < L * 2; i += BDIM) sContC[i] = gc[i];
        const int* kp = cat_p + (size_t)b * (S * 5);
        for (int i = tid; i < L * 5; i += BDIM) sCatP[i] = kp[i];
        const int* kc = cat_c + (size_t)b * (S * 2);
        for (int i = tid; i < L * 2; i += BDIM) sCatC[i] = kc[i];
    }

    // wave mapping: grp 0=ep, 1=ec, 2=hp(relu layer1), 3=hc
    // within wave: ch = channel 0..31, pr = which of 2 tokens per iteration
    const int grp = tid >> 6;
    const int ch  = tid & 31;
    const int pr  = (tid >> 5) & 1;

    // per-thread first-layer weights (column ch) in registers
    float w0 = 0.f, w1 = 0.f, w2 = 0.f, bb = 0.f;
    if (grp == 2)      { w0 = w_p1[0 * 32 + ch]; w1 = w_p1[1 * 32 + ch];
                         w2 = w_p1[2 * 32 + ch]; bb = b_p1[ch]; }
    else if (grp == 3) { w0 = w_c1[0 * 32 + ch]; w1 = w_c1[1 * 32 + ch];
                         bb = b_c1[ch]; }

    __syncthreads();

    float acc = 0.f;
    const int iters = (L + 1) >> 1;
    if (grp == 0) {
        for (int it = 0; it < iters; ++it) {
            int t = 2 * it + pr;
            if (t < L) {
                int i0 = sCatP[t * 5 + 0], i1 = sCatP[t * 5 + 1],
                    i2 = sCatP[t * 5 + 2], i3 = sCatP[t * 5 + 3],
                    i4 = sCatP[t * 5 + 4];
                acc += tb[i0 * 32 + ch] + tb[64 + i1 * 32 + ch]
                     + tb[128 + i2 * 32 + ch] + tb[192 + i3 * 32 + ch]
                     + tb[544 + i4 * 32 + ch];
            }
        }
    } else if (grp == 1) {
        for (int it = 0; it < iters; ++it) {
            int t = 2 * it + pr;
            if (t < L) {
                int j0 = sCatC[t * 2 + 0], j1 = sCatC[t * 2 + 1];
                acc += tb[1632 + j0 * 32 + ch] + tb[2240 + j1 * 32 + ch];
            }
        }
    } else if (grp == 2) {
        for (int it = 0; it < iters; ++it) {
            int t = 2 * it + pr;
            if (t < L) {
                float c0 = sContP[t * 3 + 0], c1 = sContP[t * 3 + 1],
                      c2 = sContP[t * 3 + 2];
                float v = fmaf(c0, w0, fmaf(c1, w1, fmaf(c2, w2, bb)));
                acc += fmaxf(v, 0.f);
            }
        }
    } else {
        for (int it = 0; it < iters; ++it) {
            int t = 2 * it + pr;
            if (t < L) {
                float c0 = sContC[t * 2 + 0], c1 = sContC[t * 2 + 1];
                float v = fmaf(c0, w0, fmaf(c1, w1, bb));
                acc += fmaxf(v, 0.f);
            }
        }
    }

    sRed[tid] = acc;
    __syncthreads();

    // combine the two token-parity partials; scale by group
    const float invL = 1.0f / (float)L;
    if (tid < 128) {
        int g = tid >> 5, c = tid & 31;
        float s = sRed[g * 64 + c] + sRed[g * 64 + 32 + c];
        if (g == 0)      sPooled[c]      = s * (invL * 0.2f);   // /(5L)
        else if (g == 1) sPooled[32 + c] = s * (invL * 0.5f);   // /(2L)
        else if (g == 2) sPacc[c]        = s * invL;            // pooled relu (p)
        else             sPacc[32 + c]   = s * invL;            // pooled relu (c)
    }
    __syncthreads();

    // per-row 32x32 second layers (pool and matmul commute)
    if (grp == 2 && pr == 0) {
        float v = b_p2[ch];
        #pragma unroll
        for (int k = 0; k < 32; ++k) v = fmaf(sPacc[k], w_p2[k * 32 + ch], v);
        sPooled[64 + ch] = v;
    } else if (grp == 3 && pr == 0) {
        float v = b_c2[ch];
        #pragma unroll
        for (int k = 0; k < 32; ++k) v = fmaf(sPacc[32 + k], w_c2[k * 32 + ch], v);
        sPooled[96 + ch] = v;
    }
    __syncthreads();

    // fc1: 128 -> 64, relu
    if (tid < 64) {
        float v = b_fc1[tid];
        #pragma unroll 8
        for (int k = 0; k < 128; ++k) v = fmaf(sPooled[k], w_fc1[k * 64 + tid], v);
        sH[tid] = fmaxf(v, 0.f);
    }
    __syncthreads();

    // fc2: 64 -> 2, relu
    if (tid < 2) {
        float v = b_fc2[tid];
        #pragma unroll 8
        for (int k = 0; k < 64; ++k) v = fmaf(sH[k], w_fc2[k * 2 + tid], v);
        out[(size_t)b * 2 + tid] = fmaxf(v, 0.f);
    }
}

extern "C" void kernel_launch(void* const* d_in, const int* in_sizes, int n_in,
                              void* d_out, int out_size, void* d_ws, size_t ws_size,
                              hipStream_t stream) {
    const float* cont_p = (const float*)d_in[0];
    const float* cont_c = (const float*)d_in[1];
    const int*   cat_p  = (const int*)d_in[2];
    const int*   cat_c  = (const int*)d_in[3];
    const int*   lens   = (const int*)d_in[4];
    const float* w_p1   = (const float*)d_in[5];
    const float* b_p1   = (const float*)d_in[6];
    const float* w_p2   = (const float*)d_in[7];
    const float* b_p2   = (const float*)d_in[8];
    const float* w_c1   = (const float*)d_in[9];
    const float* b_c1   = (const float*)d_in[10];
    const float* w_c2   = (const float*)d_in[11];
    const float* b_c2   = (const float*)d_in[12];
    const float* emb_g  = (const float*)d_in[13];
    const float* emb_k  = (const float*)d_in[14];
    const float* emb_pr = (const float*)d_in[15];
    const float* emb_j  = (const float*)d_in[16];
    const float* emb_r  = (const float*)d_in[17];
    const float* emb_pl = (const float*)d_in[18];
    const float* emb_a  = (const float*)d_in[19];
    const float* w_fc1  = (const float*)d_in[20];
    const float* b_fc1  = (const float*)d_in[21];
    const float* w_fc2  = (const float*)d_in[22];
    const float* b_fc2  = (const float*)d_in[23];
    float* out = (float*)d_out;

    const int B = 4096;
    hipLaunchKernelGGL(mlpreg_kernel, dim3(B), dim3(BDIM), 0, stream,
                       cont_p, cont_c, cat_p, cat_c, lens,
                       w_p1, b_p1, w_p2, b_p2, w_c1, b_c1, w_c2, b_c2,
                       emb_g, emb_k, emb_pr, emb_j, emb_r, emb_pl, emb_a,
                       w_fc1, b_fc1, w_fc2, b_fc2, out);
}

// Round 2
// 177.388 us; speedup vs baseline: 1.0724x; 1.0724x over previous
//
#include <hip/hip_runtime.h>

// One workgroup (256 threads) per batch row b in [0,4096).
// R2 changes vs R1:
//  - token data read directly from global (each element is consumed exactly
//    once -> LDS staging was pure overhead; LDS 27.6KB -> 18KB, occupancy
//    5 -> 8 WGs/CU).
//  - all 4 waves do ALL feature groups on disjoint token strides (balanced;
//    longest per-lane LDS chain drops ~2.9x; 12 independent loads/token in
//    flight for latency hiding).
//  - fc1 uses 4 accumulators to break the 128-FMA dependency chain.

#define BDIM 256

__global__ __launch_bounds__(BDIM)
void mlpreg_kernel(const float* __restrict__ cont_p,
                   const float* __restrict__ cont_c,
                   const int* __restrict__ cat_p,
                   const int* __restrict__ cat_c,
                   const int* __restrict__ lengths,
                   const float* __restrict__ w_p1, const float* __restrict__ b_p1,
                   const float* __restrict__ w_p2, const float* __restrict__ b_p2,
                   const float* __restrict__ w_c1, const float* __restrict__ b_c1,
                   const float* __restrict__ w_c2, const float* __restrict__ b_c2,
                   const float* __restrict__ emb_g,  const float* __restrict__ emb_k,
                   const float* __restrict__ emb_pr, const float* __restrict__ emb_j,
                   const float* __restrict__ emb_r,  const float* __restrict__ emb_pl,
                   const float* __restrict__ emb_a,
                   const float* __restrict__ w_fc1, const float* __restrict__ b_fc1,
                   const float* __restrict__ w_fc2, const float* __restrict__ b_fc2,
                   float* __restrict__ out)
{
    constexpr int S = 256;
    // Embedding tables concatenated, 32-float rows:
    // eg @0 (2 rows), ek @2, epr @4, ej @6 (11), er @17 (34), epl @51 (19), ea @70 (31)
    __shared__ float tb[101 * 32];       // 12928 B
    __shared__ float sRed[4][BDIM];      // 4096 B
    __shared__ float sPooled[128];       //  512 B
    __shared__ float sPacc[64];          //  256 B
    __shared__ float sH[64];             //  256 B

    const int tid = threadIdx.x;
    const int b   = blockIdx.x;
    int L = lengths[b];
    if (L < 1) L = 1;
    if (L > S) L = S;

    // ---- stage embedding tables into LDS ----
    for (int i = tid; i < 2 * 32;  i += BDIM) tb[0 * 32 + i]  = emb_g[i];
    for (int i = tid; i < 2 * 32;  i += BDIM) tb[2 * 32 + i]  = emb_k[i];
    for (int i = tid; i < 2 * 32;  i += BDIM) tb[4 * 32 + i]  = emb_pr[i];
    for (int i = tid; i < 11 * 32; i += BDIM) tb[6 * 32 + i]  = emb_j[i];
    for (int i = tid; i < 34 * 32; i += BDIM) tb[17 * 32 + i] = emb_r[i];
    for (int i = tid; i < 19 * 32; i += BDIM) tb[51 * 32 + i] = emb_pl[i];
    for (int i = tid; i < 31 * 32; i += BDIM) tb[70 * 32 + i] = emb_a[i];

    const int gid = tid >> 5;     // 0..7: token stride group
    const int ch  = tid & 31;     // channel

    // first-layer weights in registers (every lane)
    const float wp0 = w_p1[0 * 32 + ch], wp1 = w_p1[1 * 32 + ch],
                wp2 = w_p1[2 * 32 + ch], bp  = b_p1[ch];
    const float wc0 = w_c1[0 * 32 + ch], wc1 = w_c1[1 * 32 + ch],
                bc  = b_c1[ch];

    const int*   kp = cat_p  + (size_t)b * (S * 5);
    const int*   kc = cat_c  + (size_t)b * (S * 2);
    const float* gp = cont_p + (size_t)b * (S * 3);
    const float* gc = cont_c + (size_t)b * (S * 2);

    __syncthreads();

    float accP = 0.f, accC = 0.f, accHp = 0.f, accHc = 0.f;
    #pragma unroll 2
    for (int t = gid; t < L; t += 8) {
        int i0 = kp[t * 5 + 0], i1 = kp[t * 5 + 1], i2 = kp[t * 5 + 2],
            i3 = kp[t * 5 + 3], i4 = kp[t * 5 + 4];
        int j0 = kc[t * 2 + 0], j1 = kc[t * 2 + 1];
        float c0 = gp[t * 3 + 0], c1 = gp[t * 3 + 1], c2 = gp[t * 3 + 2];
        float d0 = gc[t * 2 + 0], d1 = gc[t * 2 + 1];

        accP += tb[i0 * 32 + ch] + tb[64 + i1 * 32 + ch]
              + tb[128 + i2 * 32 + ch] + tb[192 + i3 * 32 + ch]
              + tb[544 + i4 * 32 + ch];
        accC += tb[1632 + j0 * 32 + ch] + tb[2240 + j1 * 32 + ch];
        accHp += fmaxf(fmaf(c0, wp0, fmaf(c1, wp1, fmaf(c2, wp2, bp))), 0.f);
        accHc += fmaxf(fmaf(d0, wc0, fmaf(d1, wc1, bc)), 0.f);
    }

    sRed[0][tid] = accP;
    sRed[1][tid] = accC;
    sRed[2][tid] = accHp;
    sRed[3][tid] = accHc;
    __syncthreads();

    // reduce 8 stride-group partials per (output, channel); scale
    const float invL = 1.0f / (float)L;
    if (tid < 128) {
        int o = tid >> 5, c = tid & 31;
        float s = 0.f;
        #pragma unroll
        for (int g = 0; g < 8; ++g) s += sRed[o][g * 32 + c];
        if (o == 0)      sPooled[c]      = s * (invL * 0.2f);   // ep /(5L)
        else if (o == 1) sPooled[32 + c] = s * (invL * 0.5f);   // ec /(2L)
        else if (o == 2) sPacc[c]        = s * invL;            // pooled relu p
        else             sPacc[32 + c]   = s * invL;            // pooled relu c
    }
    __syncthreads();

    // per-row 32x32 second layers (pool and matmul commute: no relu between)
    if (tid >= 128 && tid < 160) {
        float v = b_p2[ch];
        #pragma unroll
        for (int k = 0; k < 32; ++k) v = fmaf(sPacc[k], w_p2[k * 32 + ch], v);
        sPooled[64 + ch] = v;
    } else if (tid >= 192 && tid < 224) {
        float v = b_c2[ch];
        #pragma unroll
        for (int k = 0; k < 32; ++k) v = fmaf(sPacc[32 + k], w_c2[k * 32 + ch], v);
        sPooled[96 + ch] = v;
    }
    __syncthreads();

    // fc1: 128 -> 64, relu (4 accumulators to break the dep chain)
    if (tid < 64) {
        float v0 = b_fc1[tid], v1 = 0.f, v2 = 0.f, v3 = 0.f;
        #pragma unroll 4
        for (int k = 0; k < 128; k += 4) {
            v0 = fmaf(sPooled[k + 0], w_fc1[(k + 0) * 64 + tid], v0);
            v1 = fmaf(sPooled[k + 1], w_fc1[(k + 1) * 64 + tid], v1);
            v2 = fmaf(sPooled[k + 2], w_fc1[(k + 2) * 64 + tid], v2);
            v3 = fmaf(sPooled[k + 3], w_fc1[(k + 3) * 64 + tid], v3);
        }
        sH[tid] = fmaxf((v0 + v1) + (v2 + v3), 0.f);
    }
    __syncthreads();

    // fc2: 64 -> 2, relu
    if (tid < 2) {
        float v0 = b_fc2[tid], v1 = 0.f;
        #pragma unroll 8
        for (int k = 0; k < 64; k += 2) {
            v0 = fmaf(sH[k],     w_fc2[k * 2 + tid],       v0);
            v1 = fmaf(sH[k + 1], w_fc2[(k + 1) * 2 + tid], v1);
        }
        out[(size_t)b * 2 + tid] = fmaxf(v0 + v1, 0.f);
    }
}

extern "C" void kernel_launch(void* const* d_in, const int* in_sizes, int n_in,
                              void* d_out, int out_size, void* d_ws, size_t ws_size,
                              hipStream_t stream) {
    const float* cont_p = (const float*)d_in[0];
    const float* cont_c = (const float*)d_in[1];
    const int*   cat_p  = (const int*)d_in[2];
    const int*   cat_c  = (const int*)d_in[3];
    const int*   lens   = (const int*)d_in[4];
    const float* w_p1   = (const float*)d_in[5];
    const float* b_p1   = (const float*)d_in[6];
    const float* w_p2   = (const float*)d_in[7];
    const float* b_p2   = (const float*)d_in[8];
    const float* w_c1   = (const float*)d_in[9];
    const float* b_c1   = (const float*)d_in[10];
    const float* w_c2   = (const float*)d_in[11];
    const float* b_c2   = (const float*)d_in[12];
    const float* emb_g  = (const float*)d_in[13];
    const float* emb_k  = (const float*)d_in[14];
    const float* emb_pr = (const float*)d_in[15];
    const float* emb_j  = (const float*)d_in[16];
    const float* emb_r  = (const float*)d_in[17];
    const float* emb_pl = (const float*)d_in[18];
    const float* emb_a  = (const float*)d_in[19];
    const float* w_fc1  = (const float*)d_in[20];
    const float* b_fc1  = (const float*)d_in[21];
    const float* w_fc2  = (const float*)d_in[22];
    const float* b_fc2  = (const float*)d_in[23];
    float* out = (float*)d_out;

    const int B = 4096;
    hipLaunchKernelGGL(mlpreg_kernel, dim3(B), dim3(BDIM), 0, stream,
                       cont_p, cont_c, cat_p, cat_c, lens,
                       w_p1, b_p1, w_p2, b_p2, w_c1, b_c1, w_c2, b_c2,
                       emb_g, emb_k, emb_pr, emb_j, emb_r, emb_pl, emb_a,
                       w_fc1, b_fc1, w_fc2, b_fc2, out);
}

// Round 3
// 146.746 us; speedup vs baseline: 1.2963x; 1.2088x over previous
//
#include <hip/hip_runtime.h>

// One workgroup (256 threads) per batch row b in [0,4096).
// R3: histogram restructure. pooled_emb = (Σ_r count[r]·emb[r])/(k·L), so we
// never stage tables in LDS and never gather per-token rows. Token reads are
// flat+coalesced; cont features staged in LDS; 7L index reads feed LDS-atomic
// histograms (4 wave-private copies to cut contention). fc1 spread over all
// 256 threads. LDS ~10KB -> 8 WG/CU (wave cap).

#define BDIM 256

__global__ __launch_bounds__(BDIM)
void mlpreg_kernel(const float* __restrict__ cont_p,
                   const float* __restrict__ cont_c,
                   const int* __restrict__ cat_p,
                   const int* __restrict__ cat_c,
                   const int* __restrict__ lengths,
                   const float* __restrict__ w_p1, const float* __restrict__ b_p1,
                   const float* __restrict__ w_p2, const float* __restrict__ b_p2,
                   const float* __restrict__ w_c1, const float* __restrict__ b_c1,
                   const float* __restrict__ w_c2, const float* __restrict__ b_c2,
                   const float* __restrict__ emb_g,  const float* __restrict__ emb_k,
                   const float* __restrict__ emb_pr, const float* __restrict__ emb_j,
                   const float* __restrict__ emb_r,  const float* __restrict__ emb_pl,
                   const float* __restrict__ emb_a,
                   const float* __restrict__ w_fc1, const float* __restrict__ b_fc1,
                   const float* __restrict__ w_fc2, const float* __restrict__ b_fc2,
                   float* __restrict__ out)
{
    constexpr int S = 256;
    __shared__ float sContP[S * 3];     // 3072 B
    __shared__ float sContC[S * 2];     // 2048 B
    __shared__ int   hist4[4][112];     // 1792 B (wave-private histograms)
    __shared__ int   histT[112];        //  448 B (totals)
    __shared__ float sRed[2][BDIM];     // 2048 B
    __shared__ float sRedF[BDIM];       // 1024 B (fc1 partials)
    __shared__ float sPooled[128];      //  512 B
    __shared__ float sPacc[64];         //  256 B
    __shared__ float sH[64];            //  256 B

    const int tid = threadIdx.x;
    const int b   = blockIdx.x;
    int L = lengths[b];
    if (L < 1) L = 1;
    if (L > S) L = S;
    const float invL = 1.0f / (float)L;

    // ---- phase 0: zero histograms ----
    for (int i = tid; i < 4 * 112; i += BDIM) ((int*)hist4)[i] = 0;
    __syncthreads();

    // ---- phase 1: coalesced staging + histogram ----
    const int*   kp = cat_p  + (size_t)b * (S * 5);
    const int*   kc = cat_c  + (size_t)b * (S * 2);
    const float* gp = cont_p + (size_t)b * (S * 3);
    const float* gc = cont_c + (size_t)b * (S * 2);

    for (int i = tid; i < L * 3; i += BDIM) sContP[i] = gp[i];
    for (int i = tid; i < L * 2; i += BDIM) sContC[i] = gc[i];

    const int wv = tid >> 6;
    // p-table bin bases: gender@0(2), korean@2(2), primary@4(2), job@6(11), rep@17(34)
    for (int i = tid; i < L * 5; i += BDIM) {
        int col = i % 5;
        int idx = kp[i];
        int base = (col == 0) ? 0 : (col == 1) ? 2 : (col == 2) ? 4
                 : (col == 3) ? 6 : 17;
        atomicAdd(&hist4[wv][base + idx], 1);
    }
    // c-table bin bases: place@51(19), add@70(31)
    for (int i = tid; i < L * 2; i += BDIM) {
        int idx = kc[i];
        atomicAdd(&hist4[wv][((i & 1) ? 70 : 51) + idx], 1);
    }
    __syncthreads();

    // ---- phase 2: hist totals (tid<112) + per-token relu MLPs (all) ----
    if (tid < 112)
        histT[tid] = hist4[0][tid] + hist4[1][tid] + hist4[2][tid] + hist4[3][tid];

    const int hw = tid >> 5;      // half-wave 0..7 = token stride group
    const int ch = tid & 31;      // channel
    const float wp0 = w_p1[0 * 32 + ch], wp1 = w_p1[1 * 32 + ch],
                wp2 = w_p1[2 * 32 + ch], bp  = b_p1[ch];
    const float wc0 = w_c1[0 * 32 + ch], wc1 = w_c1[1 * 32 + ch],
                bc  = b_c1[ch];

    float accHp = 0.f, accHc = 0.f;
    #pragma unroll 2
    for (int t = hw; t < L; t += 8) {
        float c0 = sContP[t * 3 + 0], c1 = sContP[t * 3 + 1], c2 = sContP[t * 3 + 2];
        float d0 = sContC[t * 2 + 0], d1 = sContC[t * 2 + 1];
        accHp += fmaxf(fmaf(c0, wp0, fmaf(c1, wp1, fmaf(c2, wp2, bp))), 0.f);
        accHc += fmaxf(fmaf(d0, wc0, fmaf(d1, wc1, bc)), 0.f);
    }
    sRed[0][tid] = accHp;
    sRed[1][tid] = accHc;
    __syncthreads();

    // ---- phase 3: pooled embeddings (tid<64) + pooled relu reduce (64..127) ----
    if (tid < 64) {
        int o = tid >> 5, c = tid & 31;
        if (o == 0) {
            float s0 = 0.f, s1 = 0.f;
            #pragma unroll
            for (int r = 0; r < 2; ++r)  s0 = fmaf((float)histT[0 + r],  emb_g[r * 32 + c],  s0);
            #pragma unroll
            for (int r = 0; r < 2; ++r)  s1 = fmaf((float)histT[2 + r],  emb_k[r * 32 + c],  s1);
            #pragma unroll
            for (int r = 0; r < 2; ++r)  s0 = fmaf((float)histT[4 + r],  emb_pr[r * 32 + c], s0);
            #pragma unroll
            for (int r = 0; r < 11; ++r) s1 = fmaf((float)histT[6 + r],  emb_j[r * 32 + c],  s1);
            #pragma unroll
            for (int r = 0; r < 34; ++r) s0 = fmaf((float)histT[17 + r], emb_r[r * 32 + c],  s0);
            sPooled[c] = (s0 + s1) * (invL * 0.2f);
        } else {
            float s0 = 0.f, s1 = 0.f;
            #pragma unroll
            for (int r = 0; r < 19; ++r) s0 = fmaf((float)histT[51 + r], emb_pl[r * 32 + c], s0);
            #pragma unroll
            for (int r = 0; r < 31; ++r) s1 = fmaf((float)histT[70 + r], emb_a[r * 32 + c],  s1);
            sPooled[32 + c] = (s0 + s1) * (invL * 0.5f);
        }
    } else if (tid < 128) {
        int o = (tid >> 5) - 2, c = tid & 31;   // o=0 -> Hp, o=1 -> Hc
        float s = 0.f;
        #pragma unroll
        for (int g = 0; g < 8; ++g) s += sRed[o][g * 32 + c];
        sPacc[o * 32 + c] = s * invL;
    }
    __syncthreads();

    // ---- phase 4: per-row 32x32 second layers (pool/matmul commute) ----
    if (tid >= 128 && tid < 160) {
        int c = tid & 31;
        float v = b_p2[c];
        #pragma unroll
        for (int k = 0; k < 32; ++k) v = fmaf(sPacc[k], w_p2[k * 32 + c], v);
        sPooled[64 + c] = v;
    } else if (tid >= 160 && tid < 192) {
        int c = tid & 31;
        float v = b_c2[c];
        #pragma unroll
        for (int k = 0; k < 32; ++k) v = fmaf(sPacc[32 + k], w_c2[k * 32 + c], v);
        sPooled[96 + c] = v;
    }
    __syncthreads();

    // ---- phase 5: fc1 128->64 spread over all 256 threads ----
    {
        int o = tid & 63, part = tid >> 6;
        const float* wk = w_fc1 + (size_t)(part * 32) * 64 + o;
        const float* xk = sPooled + part * 32;
        float v0 = 0.f, v1 = 0.f;
        #pragma unroll
        for (int k = 0; k < 32; k += 2) {
            v0 = fmaf(xk[k],     wk[(size_t)k * 64],       v0);
            v1 = fmaf(xk[k + 1], wk[(size_t)(k + 1) * 64], v1);
        }
        sRedF[tid] = v0 + v1;
    }
    __syncthreads();
    if (tid < 64) {
        float v = b_fc1[tid] + (sRedF[tid] + sRedF[64 + tid])
                             + (sRedF[128 + tid] + sRedF[192 + tid]);
        sH[tid] = fmaxf(v, 0.f);
    }
    __syncthreads();

    // ---- phase 6: fc2 64->2 ----
    if (tid < 2) {
        float v0 = b_fc2[tid], v1 = 0.f;
        #pragma unroll
        for (int k = 0; k < 64; k += 2) {
            v0 = fmaf(sH[k],     w_fc2[k * 2 + tid],       v0);
            v1 = fmaf(sH[k + 1], w_fc2[(k + 1) * 2 + tid], v1);
        }
        out[(size_t)b * 2 + tid] = fmaxf(v0 + v1, 0.f);
    }
}

extern "C" void kernel_launch(void* const* d_in, const int* in_sizes, int n_in,
                              void* d_out, int out_size, void* d_ws, size_t ws_size,
                              hipStream_t stream) {
    const float* cont_p = (const float*)d_in[0];
    const float* cont_c = (const float*)d_in[1];
    const int*   cat_p  = (const int*)d_in[2];
    const int*   cat_c  = (const int*)d_in[3];
    const int*   lens   = (const int*)d_in[4];
    const float* w_p1   = (const float*)d_in[5];
    const float* b_p1   = (const float*)d_in[6];
    const float* w_p2   = (const float*)d_in[7];
    const float* b_p2   = (const float*)d_in[8];
    const float* w_c1   = (const float*)d_in[9];
    const float* b_c1   = (const float*)d_in[10];
    const float* w_c2   = (const float*)d_in[11];
    const float* b_c2   = (const float*)d_in[12];
    const float* emb_g  = (const float*)d_in[13];
    const float* emb_k  = (const float*)d_in[14];
    const float* emb_pr = (const float*)d_in[15];
    const float* emb_j  = (const float*)d_in[16];
    const float* emb_r  = (const float*)d_in[17];
    const float* emb_pl = (const float*)d_in[18];
    const float* emb_a  = (const float*)d_in[19];
    const float* w_fc1  = (const float*)d_in[20];
    const float* b_fc1  = (const float*)d_in[21];
    const float* w_fc2  = (const float*)d_in[22];
    const float* b_fc2  = (const float*)d_in[23];
    float* out = (float*)d_out;

    const int B = 4096;
    hipLaunchKernelGGL(mlpreg_kernel, dim3(B), dim3(BDIM), 0, stream,
                       cont_p, cont_c, cat_p, cat_c, lens,
                       w_p1, b_p1, w_p2, b_p2, w_c1, b_c1, w_c2, b_c2,
                       emb_g, emb_k, emb_pr, emb_j, emb_r, emb_pl, emb_a,
                       w_fc1, b_fc1, w_fc2, b_fc2, out);
}

// Round 4
// 144.906 us; speedup vs baseline: 1.3128x; 1.0127x over previous
//
#include <hip/hip_runtime.h>

// R4: one 64-thread wave per batch row (grid = 4096 blocks x 64 threads).
// All cross-lane communication is intra-wave (shuffles + tiny LDS slices),
// so every __syncthreads() is a single-wave near-no-op. Histogram trick from
// R3 kept: pooled_emb = (sum_r count[r]*emb[r])/(k*L); binary-vocab columns
// need no histogram at all (count1 = sum of indices). Pool/32x32-matmul
// commute (no relu between) so second layers run once per row.

#define BDIM 64

__global__ __launch_bounds__(BDIM)
void mlpreg_kernel(const float* __restrict__ cont_p,
                   const float* __restrict__ cont_c,
                   const int* __restrict__ cat_p,
                   const int* __restrict__ cat_c,
                   const int* __restrict__ lengths,
                   const float* __restrict__ w_p1, const float* __restrict__ b_p1,
                   const float* __restrict__ w_p2, const float* __restrict__ b_p2,
                   const float* __restrict__ w_c1, const float* __restrict__ b_c1,
                   const float* __restrict__ w_c2, const float* __restrict__ b_c2,
                   const float* __restrict__ emb_g,  const float* __restrict__ emb_k,
                   const float* __restrict__ emb_pr, const float* __restrict__ emb_j,
                   const float* __restrict__ emb_r,  const float* __restrict__ emb_pl,
                   const float* __restrict__ emb_a,
                   const float* __restrict__ w_fc1, const float* __restrict__ b_fc1,
                   const float* __restrict__ w_fc2, const float* __restrict__ b_fc2,
                   float* __restrict__ out)
{
    constexpr int S = 256;
    __shared__ float sP4[S * 4];    // cont_p padded to 4 floats/token (16B LDS reads)
    __shared__ float sC2[S * 2];    // cont_c, 2 floats/token
    __shared__ int   hist[96];      // job@0(11), rep@11(34), place@45(19), add@64(31)
    __shared__ float sPacc[64];     // pooled relu sums (p | c)
    __shared__ float sPooled[128];  // [ep | ec | hp2 | hc2]

    const int lane = threadIdx.x;
    const int b    = blockIdx.x;
    int L = lengths[b];
    if (L < 1) L = 1;
    if (L > S) L = S;
    const float invL = 1.0f / (float)L;
    const float Lf   = (float)L;

    const int*   kp = cat_p  + (size_t)b * (S * 5);
    const int*   kc = cat_c  + (size_t)b * (S * 2);
    const float* gp = cont_p + (size_t)b * (S * 3);
    const float* gc = cont_c + (size_t)b * (S * 2);

    // ---- zero histogram ----
    hist[lane] = 0;
    if (lane < 32) hist[64 + lane] = 0;
    __syncthreads();

    // ---- stage cont features (lane-per-token) ----
    for (int t = lane; t < L; t += BDIM) {
        float c0 = gp[t * 3 + 0], c1 = gp[t * 3 + 1], c2 = gp[t * 3 + 2];
        float4 v; v.x = c0; v.y = c1; v.z = c2; v.w = 0.f;
        *(float4*)&sP4[t * 4] = v;
        float2 u = *(const float2*)(gc + t * 2);
        *(float2*)&sC2[t * 2] = u;
    }

    // ---- categorical pass: binary sums in registers, rest via LDS atomics ----
    int sg = 0, sk = 0, spr = 0;
    for (int i = lane; i < 5 * L; i += BDIM) {
        int v = kp[i];
        int col = i % 5;
        if      (col == 0) sg  += v;
        else if (col == 1) sk  += v;
        else if (col == 2) spr += v;
        else if (col == 3) atomicAdd(&hist[v], 1);        // job (11)
        else               atomicAdd(&hist[11 + v], 1);   // rep (34)
    }
    for (int i = lane; i < 2 * L; i += BDIM) {
        int v = kc[i];
        atomicAdd(&hist[(i & 1) ? (64 + v) : (45 + v)], 1);  // add(31) / place(19)
    }
    #pragma unroll
    for (int d = 32; d; d >>= 1) {
        sg  += __shfl_xor(sg,  d);
        sk  += __shfl_xor(sk,  d);
        spr += __shfl_xor(spr, d);
    }
    __syncthreads();

    // ---- token relu-MLP loop: half-wave pr handles tokens t%2==pr, 32 ch each ----
    const int pr = lane >> 5, ch = lane & 31;
    const float wp0 = w_p1[ch], wp1 = w_p1[32 + ch], wp2 = w_p1[64 + ch], bp = b_p1[ch];
    const float wc0 = w_c1[ch], wc1 = w_c1[32 + ch], bc = b_c1[ch];

    float accP = 0.f, accC = 0.f;
    #pragma unroll 4
    for (int t = pr; t < L; t += 2) {
        float4 cp = *(const float4*)&sP4[t * 4];
        float2 cc = *(const float2*)&sC2[t * 2];
        accP += fmaxf(fmaf(cp.x, wp0, fmaf(cp.y, wp1, fmaf(cp.z, wp2, bp))), 0.f);
        accC += fmaxf(fmaf(cc.x, wc0, fmaf(cc.y, wc1, bc)), 0.f);
    }
    accP += __shfl_down(accP, 32);
    accC += __shfl_down(accC, 32);
    if (lane < 32) {
        sPacc[ch]      = accP * invL;
        sPacc[32 + ch] = accC * invL;
    }

    // ---- pooled embeddings via histogram-weighted table sums ----
    if (pr == 0) {
        float cg = (float)sg, ck = (float)sk, cp = (float)spr;
        float s0 = fmaf(Lf - cg, emb_g[ch],  fmaf(cg, emb_g[32 + ch],
                   fmaf(Lf - ck, emb_k[ch],  ck * emb_k[32 + ch])));
        float s1 = fmaf(Lf - cp, emb_pr[ch], cp * emb_pr[32 + ch]);
        #pragma unroll
        for (int r = 0; r < 11; ++r) s0 = fmaf((float)hist[r],      emb_j[r * 32 + ch], s0);
        #pragma unroll
        for (int r = 0; r < 34; r += 2) {
            s0 = fmaf((float)hist[11 + r],     emb_r[(r + 0) * 32 + ch], s0);
            s1 = fmaf((float)hist[11 + r + 1], emb_r[(r + 1) * 32 + ch], s1);
        }
        sPooled[ch] = (s0 + s1) * (invL * 0.2f);
    } else {
        float s0 = 0.f, s1 = 0.f;
        #pragma unroll
        for (int r = 0; r < 19; ++r) s0 = fmaf((float)hist[45 + r], emb_pl[r * 32 + ch], s0);
        #pragma unroll
        for (int r = 0; r < 31; r += 2) {
            s0 = fmaf((float)hist[64 + r], emb_a[(r + 0) * 32 + ch], s0);
            if (r + 1 < 31)
                s1 = fmaf((float)hist[64 + r + 1], emb_a[(r + 1) * 32 + ch], s1);
        }
        sPooled[32 + ch] = (s0 + s1) * (invL * 0.5f);
    }
    __syncthreads();

    // ---- per-row 32x32 second layers (pool/matmul commute) ----
    if (pr == 0) {
        float v0 = b_p2[ch], v1 = 0.f;
        #pragma unroll
        for (int k = 0; k < 32; k += 2) {
            v0 = fmaf(sPacc[k],     w_p2[(k + 0) * 32 + ch], v0);
            v1 = fmaf(sPacc[k + 1], w_p2[(k + 1) * 32 + ch], v1);
        }
        sPooled[64 + ch] = v0 + v1;
    } else {
        float v0 = b_c2[ch], v1 = 0.f;
        #pragma unroll
        for (int k = 0; k < 32; k += 2) {
            v0 = fmaf(sPacc[32 + k],     w_c2[(k + 0) * 32 + ch], v0);
            v1 = fmaf(sPacc[32 + k + 1], w_c2[(k + 1) * 32 + ch], v1);
        }
        sPooled[96 + ch] = v0 + v1;
    }
    __syncthreads();

    // ---- fc1: 128 -> 64, one output per lane ----
    const float* wk = w_fc1 + lane;
    float v0 = b_fc1[lane], v1 = 0.f, v2 = 0.f, v3 = 0.f;
    #pragma unroll 8
    for (int k = 0; k < 128; k += 4) {
        float4 x = *(const float4*)&sPooled[k];
        v0 = fmaf(x.x, wk[(size_t)(k + 0) * 64], v0);
        v1 = fmaf(x.y, wk[(size_t)(k + 1) * 64], v1);
        v2 = fmaf(x.z, wk[(size_t)(k + 2) * 64], v2);
        v3 = fmaf(x.w, wk[(size_t)(k + 3) * 64], v3);
    }
    float h = fmaxf((v0 + v1) + (v2 + v3), 0.f);

    // ---- fc2: 64 -> 2 via butterfly reduce ----
    float p0 = h * w_fc2[lane * 2 + 0];
    float p1 = h * w_fc2[lane * 2 + 1];
    #pragma unroll
    for (int d = 32; d; d >>= 1) {
        p0 += __shfl_xor(p0, d);
        p1 += __shfl_xor(p1, d);
    }
    if (lane == 0) {
        float2 o;
        o.x = fmaxf(p0 + b_fc2[0], 0.f);
        o.y = fmaxf(p1 + b_fc2[1], 0.f);
        *(float2*)&out[(size_t)b * 2] = o;
    }
}

extern "C" void kernel_launch(void* const* d_in, const int* in_sizes, int n_in,
                              void* d_out, int out_size, void* d_ws, size_t ws_size,
                              hipStream_t stream) {
    const float* cont_p = (const float*)d_in[0];
    const float* cont_c = (const float*)d_in[1];
    const int*   cat_p  = (const int*)d_in[2];
    const int*   cat_c  = (const int*)d_in[3];
    const int*   lens   = (const int*)d_in[4];
    const float* w_p1   = (const float*)d_in[5];
    const float* b_p1   = (const float*)d_in[6];
    const float* w_p2   = (const float*)d_in[7];
    const float* b_p2   = (const float*)d_in[8];
    const float* w_c1   = (const float*)d_in[9];
    const float* b_c1   = (const float*)d_in[10];
    const float* w_c2   = (const float*)d_in[11];
    const float* b_c2   = (const float*)d_in[12];
    const float* emb_g  = (const float*)d_in[13];
    const float* emb_k  = (const float*)d_in[14];
    const float* emb_pr = (const float*)d_in[15];
    const float* emb_j  = (const float*)d_in[16];
    const float* emb_r  = (const float*)d_in[17];
    const float* emb_pl = (const float*)d_in[18];
    const float* emb_a  = (const float*)d_in[19];
    const float* w_fc1  = (const float*)d_in[20];
    const float* b_fc1  = (const float*)d_in[21];
    const float* w_fc2  = (const float*)d_in[22];
    const float* b_fc2  = (const float*)d_in[23];
    float* out = (float*)d_out;

    const int B = 4096;
    hipLaunchKernelGGL(mlpreg_kernel, dim3(B), dim3(BDIM), 0, stream,
                       cont_p, cont_c, cat_p, cat_c, lens,
                       w_p1, b_p1, w_p2, b_p2, w_c1, b_c1, w_c2, b_c2,
                       emb_g, emb_k, emb_pr, emb_j, emb_r, emb_pl, emb_a,
                       w_fc1, b_fc1, w_fc2, b_fc2, out);
}